// Round 1
// baseline (161.331 us; speedup 1.0000x reference)
//
#include <hip/hip_runtime.h>

// LaplacianLoss on a fixed 512x512 grid mesh, B=32.
// Lv[b,(i,j)] = v - (1/deg)*sum(nbrs), nbrs = (i,j+-1),(i+-1,j),(i-1,j+1),(i+1,j-1)
// out = mean over (B,V) of |Lv|^2.
//
// R6: coalesced float4 global->LDS staging, 2-slot rolling LDS window, one
// barrier per row. R7 (this): (1) depth-2 alternating register prefetch --
// the global load issued at iter k is staged at iter k+2, giving ~2 barriers
// + 2 compute phases to hide ~900cy HBM latency (was 1); (2) stencil LDS
// reads widened from 12x ds_read_b32 (all 4-way bank-conflicted, addr=6t+c)
// to 7x 8B-aligned reads (6t is always even -> float2 casts are legal).
// Halo is 7 zero words per slot (1536..1542) so t==0 / t==255 wide reads
// need no masks.

#define GH 512
#define GW 512
#define GV (GH * GW)
#define RI 16
#define NCHUNK (GH / RI)           // 32
#define ROWF (GW * 3)              // 1536 floats per global row
#define LROW 1544                  // LDS row stride (floats): 1536 data + 7 halo + 1 pad
#define NITER (RI + 2)             // 18
#define NBLK (32 * NCHUNK)         // 1024

__device__ __forceinline__ void load_row(const float* __restrict__ base, int r, int t,
                                         float4& r0, float4& r1) {
    if (r >= 0 && r < GH) {
        const float4* rp = (const float4*)(base + (size_t)r * ROWF);
        r0 = rp[t];
        r1 = (t < 128) ? rp[256 + t] : make_float4(0.f, 0.f, 0.f, 0.f);
    } else {
        r0 = make_float4(0.f, 0.f, 0.f, 0.f);
        r1 = r0;
    }
}

__global__ __launch_bounds__(256, 4) void lap_partial_kernel(
    const float* __restrict__ verts, float* __restrict__ partials) {
    __shared__ float lds[2 * LROW];            // 12.3 KB

    const int bid   = blockIdx.x;
    const int batch = bid >> 5;
    const int chunk = bid & (NCHUNK - 1);
    const int i0    = chunk * RI;
    const int t     = threadIdx.x;
    const float* __restrict__ base = verts + (size_t)batch * (GV * 3);

    // zero halo floats (7 words per slot: 1536..1542) once; never rewritten
    if (t < 14) {
        const int slot = t / 7, o = t - 7 * slot;
        lds[slot * LROW + 1536 + o] = 0.0f;
    }

    // thread owns cols 2t (even) and 2t+1 (odd)
    const float jle = (t > 0)   ? 1.f : 0.f;   // even col has left nbr
    const float jro = (t < 255) ? 1.f : 0.f;   // odd col has right nbr

    // word offsets into the LDS row (all even -> 8B-aligned float2 reads)
    const int wE  = 6 * t;                              // [Ex,Ey][Ez,Ox][Oy,Oz]
    const int wLA = (t == 0)   ? 1536 : (6 * t - 4);    // [.,Lx][Ly,Lz]
    const int wR0 = (t == 255) ? 1540 : (6 * t + 6);    // [Rx,Ry] + b32 Rz

    // -1/deg, deg = (ht+hb) + jl*(1+hb) + jr*(1+ht)
    const float invE_m = -1.f / (4.f + 2.f * jle);
    const float invO_m = -1.f / (4.f + 2.f * jro);
    const float invE_t = -1.f / (2.f + 2.f * jle);
    const float invO_t = -1.f / (3.f + jro);
    const float invE_b = -1.f / (3.f + jle);
    const float invO_b = -1.f / (2.f + 2.f * jro);

    // depth-2 prefetch: a staged at even k, b staged at odd k.
    // a holds row i0-1 (staged k=0), b holds row i0 (staged k=1).
    float4 a0, a1, b0, b1;
    load_row(base, i0 - 1, t, a0, a1);
    load_row(base, i0,     t, b0, b1);
    __syncthreads();   // halo zeros visible before first reads

    // carried state: T2=T(c-1), T1=T(c), M1=M(c), C1=C(c)  (6 floats each)
    float T2Ex=0,T2Ey=0,T2Ez=0, T2Ox=0,T2Oy=0,T2Oz=0;
    float T1Ex=0,T1Ey=0,T1Ez=0, T1Ox=0,T1Oy=0,T1Oz=0;
    float M1Ex=0,M1Ey=0,M1Ez=0, M1Ox=0,M1Oy=0,M1Oz=0;
    float C1Ex=0,C1Ey=0,C1Ez=0, C1Ox=0,C1Oy=0,C1Oz=0;
    float local = 0.f;

    #pragma unroll
    for (int k = 0; k < NITER; ++k) {
        float* lp = lds + (k & 1) * LROW;
        const bool even = ((k & 1) == 0);

        // stage row n = i0-1+k from the register set loaded 2 iters ago
        if (even) {
            *(float4*)(lp + 4 * t) = a0;
            if (t < 128) *(float4*)(lp + 1024 + 4 * t) = a1;
        } else {
            *(float4*)(lp + 4 * t) = b0;
            if (t < 128) *(float4*)(lp + 1024 + 4 * t) = b1;
        }

        // issue load of row i0+k+1 (= staged at iter k+2): 2 iters of latency slack
        if (k < NITER - 2) {
            const int rn = i0 + k + 1;
            if (even) load_row(base, rn, t, a0, a1);
            else      load_row(base, rn, t, b0, b1);
        }
        __syncthreads();

        // read new row n: 7 wide 8B-aligned reads (was 12 scalar, 4-way conflicted)
        const float2 e01  = *(const float2*)(lp + wE);        // Ex, Ey
        const float2 e2o0 = *(const float2*)(lp + wE + 2);    // Ez, Ox
        const float2 o12  = *(const float2*)(lp + wE + 4);    // Oy, Oz
        const float2 lA   = *(const float2*)(lp + wLA);       // _, Lx
        const float2 lB   = *(const float2*)(lp + wLA + 2);   // Ly, Lz
        const float2 rA   = *(const float2*)(lp + wR0);       // Rx, Ry
        const float  Rz   = lp[wR0 + 2];

        const float Ex = e01.x,  Ey = e01.y,  Ez = e2o0.x;
        const float Ox = e2o0.y, Oy = o12.x,  Oz = o12.y;
        const float Lx = lA.y,   Ly = lB.x,   Lz = lB.y;
        const float Rx = rA.x,   Ry = rA.y;

        // combos for row n:  B = C+L (bottom contrib), T = C+R, M = L+R
        const float BnEx = Ex + Lx, BnEy = Ey + Ly, BnEz = Ez + Lz;
        const float BnOx = Ox + Ex, BnOy = Oy + Ey, BnOz = Oz + Ez;
        const float TnEx = Ex + Ox, TnEy = Ey + Oy, TnEz = Ez + Oz;
        const float TnOx = Ox + Rx, TnOy = Oy + Ry, TnOz = Oz + Rz;
        const float MnEx = Lx + Ox, MnEy = Ly + Oy, MnEz = Lz + Oz;
        const float MnOx = Ex + Rx, MnOy = Ey + Ry, MnOz = Ez + Rz;

        // finalize center c = i0+k-2: sum = T(c-1) + M(c) + B(c+1)
        if (k >= 2) {
            const int c = i0 + k - 2;
            float invE = invE_m, invO = invO_m;
            if (c == 0)            { invE = invE_t; invO = invO_t; }
            else if (c == GH - 1)  { invE = invE_b; invO = invO_b; }

            float s, lv;
            s = T2Ex + M1Ex + BnEx; lv = fmaf(invE, s, C1Ex); local = fmaf(lv, lv, local);
            s = T2Ey + M1Ey + BnEy; lv = fmaf(invE, s, C1Ey); local = fmaf(lv, lv, local);
            s = T2Ez + M1Ez + BnEz; lv = fmaf(invE, s, C1Ez); local = fmaf(lv, lv, local);
            s = T2Ox + M1Ox + BnOx; lv = fmaf(invO, s, C1Ox); local = fmaf(lv, lv, local);
            s = T2Oy + M1Oy + BnOy; lv = fmaf(invO, s, C1Oy); local = fmaf(lv, lv, local);
            s = T2Oz + M1Oz + BnOz; lv = fmaf(invO, s, C1Oz); local = fmaf(lv, lv, local);
        }

        // rotate: T2<-T1, T1<-Tn, M1<-Mn, C1<-Cn
        T2Ex = T1Ex; T2Ey = T1Ey; T2Ez = T1Ez; T2Ox = T1Ox; T2Oy = T1Oy; T2Oz = T1Oz;
        T1Ex = TnEx; T1Ey = TnEy; T1Ez = TnEz; T1Ox = TnOx; T1Oy = TnOy; T1Oz = TnOz;
        M1Ex = MnEx; M1Ey = MnEy; M1Ez = MnEz; M1Ox = MnOx; M1Oy = MnOy; M1Oz = MnOz;
        C1Ex = Ex;   C1Ey = Ey;   C1Ez = Ez;   C1Ox = Ox;   C1Oy = Oy;   C1Oz = Oz;
    }

    // block reduction: wave shuffle -> LDS -> one store per block
    #pragma unroll
    for (int off = 32; off > 0; off >>= 1)
        local += __shfl_down(local, off, 64);

    __shared__ float wsum[4];
    const int lane = t & 63;
    const int wave = t >> 6;
    if (lane == 0) wsum[wave] = local;
    __syncthreads();
    if (t == 0)
        partials[bid] = wsum[0] + wsum[1] + wsum[2] + wsum[3];
}

__global__ __launch_bounds__(256) void lap_final_kernel(
    const float* __restrict__ partials, float* __restrict__ out, int nblk, int B) {
    float local = 0.0f;
    for (int k = threadIdx.x; k < nblk; k += 256)
        local += partials[k];

    #pragma unroll
    for (int off = 32; off > 0; off >>= 1)
        local += __shfl_down(local, off, 64);

    __shared__ float wsum[4];
    const int lane = threadIdx.x & 63;
    const int wid  = threadIdx.x >> 6;
    if (lane == 0) wsum[wid] = local;
    __syncthreads();

    if (threadIdx.x == 0) {
        const float s = wsum[0] + wsum[1] + wsum[2] + wsum[3];
        out[0] = s / ((float)B * (float)GV);
    }
}

extern "C" void kernel_launch(void* const* d_in, const int* in_sizes, int n_in,
                              void* d_out, int out_size, void* d_ws, size_t ws_size,
                              hipStream_t stream) {
    const float* verts = (const float*)d_in[0];
    float* out = (float*)d_out;
    float* partials = (float*)d_ws;            // 1024 floats = 4 KB

    const int B = in_sizes[0] / (GV * 3);      // 32

    lap_partial_kernel<<<NBLK, 256, 0, stream>>>(verts, partials);
    lap_final_kernel<<<1, 256, 0, stream>>>(partials, out, NBLK, B);
}